// Round 5
// baseline (35.388 us; speedup 1.0000x reference)
//
#include <hip/hip_runtime.h>

// RandomResizedCrop N=128,C=3,H=W=256 fp32.
// R5: 4-row stripes (5 staged rows, LDS 15.4KB -> 8 blocks/CU = 100% waves),
// ds_read2-paired LDS gathers, nontemporal output stores (native vec type).

constexpr int N_ = 128, C_ = 3, H_ = 256, W_ = 256, HW_ = H_ * W_;
constexpr int ROWS_ = 5;                      // max staged input rows per 4-row stripe
constexpr int LDSF_ = C_ * ROWS_ * W_ + 4;    // +4 pad: weight-zeroed ix0+1 over-read

typedef float f32x4 __attribute__((ext_vector_type(4)));

__device__ __forceinline__ void coord(float scale, float bias, float xf, int size,
                                      int& i0, int& i1, float& w) {
    const float span = (float)size;
    const float two  = 2.0f * span;
    float xs  = (xf + 0.5f) * (2.0f / span) - 1.0f;
    float g   = scale * xs + bias;
    float pre = ((g + 1.0f) * span - 1.0f) * 0.5f;
    float t = fabsf(pre + 0.5f);
    t = t - two * floorf(t * (1.0f / two));   // exact fmod(t, 512), pow2 span
    t = (t > span) ? (two - t) : t;
    t -= 0.5f;
    t = fminf(fmaxf(t, 0.0f), span - 1.0f);
    float f = floorf(t);
    w  = t - f;
    i0 = (int)f;
    i1 = min(i0 + 1, size - 1);
}

__global__ __launch_bounds__(256, 8)
void rrc_kernel(const float* __restrict__ in, const float* __restrict__ wh,
                float* __restrict__ out) {
    __shared__ float lds[LDSF_];
    const int n   = blockIdx.x >> 6;         // image
    const int ys  = (blockIdx.x & 63) * 4;   // 4-row output stripe
    const int tid = threadIdx.x;
    const int xq  = tid & 63;                // x = 4*xq..4*xq+3
    const int yl  = tid >> 6;                // this thread's row (0..3)

    const float w_s = wh[n * 4 + 0];
    const float h_s = wh[n * 4 + 1];
    const float w_b = wh[n * 4 + 2];
    const float h_b = wh[n * 4 + 3];

    // y-coords for all 4 rows (unrolled; capture own row via predicated select).
    int rmin = H_ - 1, rmax = 0;
    int my0 = 0;  float wy = 0.0f;
#pragma unroll
    for (int r = 0; r < 4; ++r) {
        int a, b; float w;
        coord(h_s, h_b, (float)(ys + r), H_, a, b, w);
        rmin = min(rmin, a);
        rmax = max(rmax, b);
        if (r == yl) { my0 = a; wy = w; }
    }
    const int nrows = rmax - rmin + 1;       // <= 5 (coordinate map is 1-Lipschitz)

    // Stage rows [rmin,rmax] x 3 channels, coalesced float4.
    const float* __restrict__ inN = in + (size_t)n * C_ * HW_;
#pragma unroll
    for (int c = 0; c < C_; ++c) {
        for (int r = yl; r < nrows; r += 4) {
            const f32x4 v = *reinterpret_cast<const f32x4*>(
                inN + c * HW_ + (rmin + r) * W_ + xq * 4);
            *reinterpret_cast<f32x4*>(&lds[(c * ROWS_ + r) * W_ + xq * 4]) = v;
        }
    }
    __syncthreads();

    // Per-thread x coords (ix1 handled implicitly: lds[i+1]; at ix0=255 wx==0).
    int ix0[4]; float wx[4];
#pragma unroll
    for (int j = 0; j < 4; ++j) {
        int i1_unused;
        coord(w_s, w_b, (float)(xq * 4 + j), W_, ix0[j], i1_unused, wx[j]);
    }

    float* __restrict__ outN = out + (size_t)n * C_ * HW_;

    const int y  = ys + yl;
    const int b0 = (my0 - rmin) * W_;
    const int b1 = min(my0 + 1, H_ - 1) >= rmax ? (rmax - rmin) * W_
                                                : (my0 + 1 - rmin) * W_;
#pragma unroll
    for (int c = 0; c < C_; ++c) {
        const int co = c * ROWS_ * W_;
        f32x4 o;
#pragma unroll
        for (int j = 0; j < 4; ++j) {
            const int a0 = co + b0 + ix0[j];
            const int a1 = co + b1 + ix0[j];
            const float v00 = lds[a0];
            const float v01 = lds[a0 + 1];    // pairs into ds_read2_b32
            const float v10 = lds[a1];
            const float v11 = lds[a1 + 1];
            const float top = v00 + wx[j] * (v01 - v00);
            const float bot = v10 + wx[j] * (v11 - v10);
            o[j] = top + wy * (bot - top);
        }
        __builtin_nontemporal_store(o, reinterpret_cast<f32x4*>(
            outN + (c * H_ + y) * W_ + xq * 4));
    }
}

extern "C" void kernel_launch(void* const* d_in, const int* in_sizes, int n_in,
                              void* d_out, int out_size, void* d_ws, size_t ws_size,
                              hipStream_t stream) {
    const float* in = (const float*)d_in[0];
    const float* wh = (const float*)d_in[1];
    float* out      = (float*)d_out;
    (void)in_sizes; (void)n_in; (void)out_size; (void)d_ws; (void)ws_size;

    dim3 grid(N_ * 64);  // 128 images x 64 stripes of 4 rows
    dim3 block(256);
    rrc_kernel<<<grid, block, 0, stream>>>(in, wh, out);
}

// Round 6
// 35.308 us; speedup vs baseline: 1.0022x; 1.0022x over previous
//
#include <hip/hip_runtime.h>

// RandomResizedCrop N=128,C=3,H=W=256 fp32 — separable two-stage resize.
// R6: cut scattered-LDS words 3.2x: stage raw rows -> hlerp once per staged
// row (thread owns one x; 5 ds_read2 + 5 stride-1 writes per ch) -> vlerp
// from H with wave-uniform-row, lane-contiguous ds_read_b128 (conflict-free).

constexpr int N_ = 128, C_ = 3, H_ = 256, W_ = 256, HW_ = H_ * W_;
constexpr int ROWS_ = 5;                         // max staged rows per 4-row stripe

typedef float f32x4 __attribute__((ext_vector_type(4)));

__device__ __forceinline__ void coord(float scale, float bias, float xf, int size,
                                      int& i0, float& w) {
    const float span = (float)size;
    const float two  = 2.0f * span;
    float xs  = (xf + 0.5f) * (2.0f / span) - 1.0f;
    float g   = scale * xs + bias;
    float pre = ((g + 1.0f) * span - 1.0f) * 0.5f;
    float t = fabsf(pre + 0.5f);
    t = t - two * floorf(t * (1.0f / two));   // exact fmod(t, 512), pow2 span
    t = (t > span) ? (two - t) : t;
    t -= 0.5f;
    t = fminf(fmaxf(t, 0.0f), span - 1.0f);
    float f = floorf(t);
    w  = t - f;
    i0 = (int)f;                              // i0==size-1  =>  w==0 exactly
}

__global__ __launch_bounds__(256)
void rrc_kernel(const float* __restrict__ in, const float* __restrict__ wh,
                float* __restrict__ out) {
    __shared__ float raw[ROWS_ * W_ + 4];     // +pad: ix+1 over-read is weight-0
    __shared__ float Hl[ROWS_ * W_];

    const int n   = blockIdx.x >> 6;          // image
    const int ys  = (blockIdx.x & 63) * 4;    // 4-row output stripe
    const int tid = threadIdx.x;
    const int xq  = tid & 63;                 // vlerp: x = 4*xq..4*xq+3
    const int yl  = tid >> 6;                 // vlerp row (wave-uniform)

    const float w_s = wh[n * 4 + 0];
    const float h_s = wh[n * 4 + 1];
    const float w_b = wh[n * 4 + 2];
    const float h_b = wh[n * 4 + 3];

    // y-coords for the 4 output rows; own row captured by predicated select.
    int rmin = H_ - 1, rmax = 0;
    int my0 = 0; float wy = 0.0f;
#pragma unroll
    for (int r = 0; r < 4; ++r) {
        int a; float w;
        coord(h_s, h_b, (float)(ys + r), H_, a, w);
        rmin = min(rmin, a);
        rmax = max(rmax, min(a + 1, H_ - 1));
        if (r == yl) { my0 = a; wy = w; }
    }
    const int nrows = rmax - rmin + 1;        // 2..5 (coord map is 1-Lipschitz)
    const int words = nrows * 64;             // float4 chunks to stage
    const int b0 = (my0 - rmin) * W_;
    const int b1 = (min(my0 + 1, H_ - 1) - rmin) * W_;

    // Issue ALL channels' staging loads up front (hide HBM latency).
    const float* __restrict__ inN = in + (size_t)n * C_ * HW_;
    const int r0 = tid >> 6,          sx0 = (tid & 63) * 4;   // chunk tid
    const int r1 = (tid + 256) >> 6,  sx1 = sx0;              // chunk tid+256
    const bool m1 = (tid + 256) < words;                      // r0 always < 4 <= nrows? no:
    const bool m0 = tid < words;                              // nrows can be 2,3
    f32x4 ga[C_], gb[C_];
#pragma unroll
    for (int c = 0; c < C_; ++c) {
        if (m0) ga[c] = *reinterpret_cast<const f32x4*>(
            inN + c * HW_ + (rmin + r0) * W_ + sx0);
        if (m1) gb[c] = *reinterpret_cast<const f32x4*>(
            inN + c * HW_ + (rmin + r1) * W_ + sx1);
    }

    // hlerp x-coordinate: this thread owns x = tid.
    int hix; float hwx;
    coord(w_s, w_b, (float)tid, W_, hix, hwx);

    float* __restrict__ outN = out + (size_t)n * C_ * HW_;

#pragma unroll
    for (int c = 0; c < C_; ++c) {
        // stage raw rows for channel c
        if (m0) *reinterpret_cast<f32x4*>(&raw[r0 * W_ + sx0]) = ga[c];
        if (m1) *reinterpret_cast<f32x4*>(&raw[r1 * W_ + sx1]) = gb[c];
        __syncthreads();
        // hlerp: H[k][tid] for all staged rows (k>=nrows unused, never read)
#pragma unroll
        for (int k = 0; k < ROWS_; ++k) {
            const float a = raw[k * W_ + hix];
            const float b = raw[k * W_ + hix + 1];   // ds_read2; weight-0 if hix==255
            Hl[k * W_ + tid] = a + hwx * (b - a);
        }
        __syncthreads();
        // vlerp: wave-uniform rows, lane-contiguous b128 reads — conflict-free
        const f32x4 h0 = *reinterpret_cast<const f32x4*>(&Hl[b0 + xq * 4]);
        const f32x4 h1 = *reinterpret_cast<const f32x4*>(&Hl[b1 + xq * 4]);
        const f32x4 o  = h0 + wy * (h1 - h0);
        __builtin_nontemporal_store(o, reinterpret_cast<f32x4*>(
            outN + (c * H_ + ys + yl) * W_ + xq * 4));
    }
}

extern "C" void kernel_launch(void* const* d_in, const int* in_sizes, int n_in,
                              void* d_out, int out_size, void* d_ws, size_t ws_size,
                              hipStream_t stream) {
    const float* in = (const float*)d_in[0];
    const float* wh = (const float*)d_in[1];
    float* out      = (float*)d_out;
    (void)in_sizes; (void)n_in; (void)out_size; (void)d_ws; (void)ws_size;

    dim3 grid(N_ * 64);  // 128 images x 64 stripes of 4 rows
    dim3 block(256);
    rrc_kernel<<<grid, block, 0, stream>>>(in, wh, out);
}

// Round 7
// 34.343 us; speedup vs baseline: 1.0304x; 1.0281x over previous
//
#include <hip/hip_runtime.h>

// RandomResizedCrop N=128,C=3,H=W=256 fp32 — vlerp-first, barrier-free.
// Each thread: own output row. vlerp in registers from 2 coalesced global row
// loads; V row -> wave-private LDS segment (skewed, conflict-free); hlerp
// gathers from V. No __syncthreads anywhere (DS pipe is in-order per wave).

constexpr int N_ = 128, C_ = 3, H_ = 256, W_ = 256, HW_ = H_ * W_;
constexpr int SEG_ = 264;   // words per (row,ch) V-segment: skew maps 0..255 -> 0..262

typedef float f32x4 __attribute__((ext_vector_type(4)));

__device__ __forceinline__ void coord(float scale, float bias, float xf, int size,
                                      int& i0, float& w) {
    const float span = (float)size;
    const float two  = 2.0f * span;
    float xs  = (xf + 0.5f) * (2.0f / span) - 1.0f;
    float g   = scale * xs + bias;
    float pre = ((g + 1.0f) * span - 1.0f) * 0.5f;
    float t = fabsf(pre + 0.5f);
    t = t - two * floorf(t * (1.0f / two));   // exact fmod(t, 512), pow2 span
    t = (t > span) ? (two - t) : t;
    t -= 0.5f;
    t = fminf(fmaxf(t, 0.0f), span - 1.0f);
    float f = floorf(t);
    w  = t - f;
    i0 = (int)f;                              // i0 == size-1  =>  w == 0 exactly
}

__global__ __launch_bounds__(256)
void rrc_kernel(const float* __restrict__ in, const float* __restrict__ wh,
                float* __restrict__ out) {
    __shared__ float V[4 * C_ * SEG_];        // 12 wave-private segments, 12.7 KB
    const int n   = blockIdx.x >> 6;          // image
    const int ys  = (blockIdx.x & 63) * 4;    // 4-row output stripe
    const int tid = threadIdx.x;
    const int xq  = tid & 63;                 // x-quad: x = 4*xq..4*xq+3
    const int yl  = tid >> 6;                 // own output row = wave index

    const float w_s = wh[n * 4 + 0];
    const float h_s = wh[n * 4 + 1];
    const float w_b = wh[n * 4 + 2];
    const float h_b = wh[n * 4 + 3];

    // Own row's y-coordinate only.
    int iy0; float wy;
    coord(h_s, h_b, (float)(ys + yl), H_, iy0, wy);
    const int iy1 = min(iy0 + 1, H_ - 1);     // wy==0 when clamped

    // x-coords + skewed gather offsets (addr(x) = x + (x>>5), bijective).
    int offA[4], offB[4]; float wx[4];
#pragma unroll
    for (int j = 0; j < 4; ++j) {
        int i0;
        coord(w_s, w_b, (float)(xq * 4 + j), W_, i0, wx[j]);
        const int xb = min(i0 + 1, W_ - 1);   // wx==0 when clamped -> o = a exactly
        offA[j] = i0 + (i0 >> 5);
        offB[j] = xb + (xb >> 5);
    }

    // Preload all 3 channels' row pairs (6 coalesced f32x4 loads in flight).
    const float* __restrict__ inN = in + (size_t)n * C_ * HW_;
    f32x4 g0[C_], g1[C_];
#pragma unroll
    for (int c = 0; c < C_; ++c) {
        g0[c] = *reinterpret_cast<const f32x4*>(inN + c * HW_ + iy0 * W_ + xq * 4);
        g1[c] = *reinterpret_cast<const f32x4*>(inN + c * HW_ + iy1 * W_ + xq * 4);
    }

    float* __restrict__ outN = out + (size_t)n * C_ * HW_;
    const int segBase = yl * C_ * SEG_;
    const int woff    = xq * 4 + (xq >> 3);   // skewed write offset (4 words stay contiguous)

#pragma unroll
    for (int c = 0; c < C_; ++c) {
        const f32x4 v = g0[c] + wy * (g1[c] - g0[c]);   // vlerp in registers
        float* seg = &V[segBase + c * SEG_];
        *reinterpret_cast<f32x4*>(seg + woff) = v;      // 1 ds_write_b128
        // Same-wave DS ops are in-order: reads below see all lanes' writes.
        f32x4 o;
#pragma unroll
        for (int j = 0; j < 4; ++j) {
            const float a = seg[offA[j]];
            const float b = seg[offB[j]];
            o[j] = a + wx[j] * (b - a);                 // hlerp
        }
        *reinterpret_cast<f32x4*>(outN + (c * H_ + ys + yl) * W_ + xq * 4) = o;
    }
}

extern "C" void kernel_launch(void* const* d_in, const int* in_sizes, int n_in,
                              void* d_out, int out_size, void* d_ws, size_t ws_size,
                              hipStream_t stream) {
    const float* in = (const float*)d_in[0];
    const float* wh = (const float*)d_in[1];
    float* out      = (float*)d_out;
    (void)in_sizes; (void)n_in; (void)out_size; (void)d_ws; (void)ws_size;

    dim3 grid(N_ * 64);  // 128 images x 64 stripes of 4 rows
    dim3 block(256);
    rrc_kernel<<<grid, block, 0, stream>>>(in, wh, out);
}